// Round 1
// baseline (453.536 us; speedup 1.0000x reference)
//
#include <hip/hip_runtime.h>

#define D     4096   // row length
#define KKEEP 512    // entries to keep per row
#define TPB   256    // threads per block (one block per row)
#define EPT   16     // elements per thread (D / TPB)

// Monotonic float -> uint key: preserves total order of floats as unsigned ints.
__device__ __forceinline__ unsigned key_of(float f) {
    unsigned u = __float_as_uint(f);
    return (u & 0x80000000u) ? ~u : (u | 0x80000000u);
}
// Exact inverse of key_of.
__device__ __forceinline__ float val_of(unsigned k) {
    unsigned u = (k & 0x80000000u) ? (k ^ 0x80000000u) : ~k;
    return __uint_as_float(u);
}

__global__ __launch_bounds__(TPB, 8)
void topk_keep_kernel(const float* __restrict__ x, float* __restrict__ out) {
    const int tid = threadIdx.x;
    const long base = (long)blockIdx.x * D + (long)tid * EPT;

    // ---- Load 16 floats (4x float4, contiguous chunk per thread), keys in regs
    unsigned k[EPT];
    {
        const float4* px = (const float4*)(x + base);
        float4 f0 = px[0], f1 = px[1], f2 = px[2], f3 = px[3];
        k[ 0]=key_of(f0.x); k[ 1]=key_of(f0.y); k[ 2]=key_of(f0.z); k[ 3]=key_of(f0.w);
        k[ 4]=key_of(f1.x); k[ 5]=key_of(f1.y); k[ 6]=key_of(f1.z); k[ 7]=key_of(f1.w);
        k[ 8]=key_of(f2.x); k[ 9]=key_of(f2.y); k[10]=key_of(f2.z); k[11]=key_of(f2.w);
        k[12]=key_of(f3.x); k[13]=key_of(f3.y); k[14]=key_of(f3.z); k[15]=key_of(f3.w);
    }

    __shared__ unsigned hist[256];
    __shared__ unsigned s_sel[2];          // [selected digit, new remaining]
    __shared__ unsigned s_wsum[TPB / 64];  // per-wave equal-count totals

    unsigned prefix = 0;   // selected high bits of threshold key (aligned in place)
    unsigned rem = KKEEP;  // rank still to satisfy within current prefix subset

    // ---- 4-round radix select (8 bits per round, MSB first) for k-th largest
    #pragma unroll
    for (int r = 0; r < 4; ++r) {
        const int shift = 24 - 8 * r;
        hist[tid] = 0;
        __syncthreads();

        if (r == 0) {
            #pragma unroll
            for (int j = 0; j < EPT; ++j)
                atomicAdd(&hist[k[j] >> 24], 1u);
        } else {
            const int hs = shift + 8;  // bits already decided
            #pragma unroll
            for (int j = 0; j < EPT; ++j)
                if ((k[j] >> hs) == (prefix >> hs))
                    atomicAdd(&hist[(k[j] >> shift) & 255u], 1u);
        }
        __syncthreads();

        // Single-wave suffix scan over 256 bins (4 bins/lane), pick digit where
        // the cumulative count from the top reaches `rem`.
        if (tid < 64) {
            unsigned c0 = hist[tid * 4 + 0], c1 = hist[tid * 4 + 1];
            unsigned c2 = hist[tid * 4 + 2], c3 = hist[tid * 4 + 3];
            unsigned lt = c0 + c1 + c2 + c3;
            unsigned s = lt;
            #pragma unroll
            for (int off = 1; off < 64; off <<= 1) {
                unsigned t = __shfl_down(s, off, 64);
                if (tid + off < 64) s += t;
            }
            // s = inclusive suffix sum over lanes [tid..63]
            unsigned sx = s - lt;            // exclusive (lanes above)
            unsigned si3 = sx + c3;
            unsigned si2 = si3 + c2;
            unsigned si1 = si2 + c1;
            unsigned si0 = si1 + c0;
            // exactly one bin satisfies (suffix_incl >= rem && suffix_excl < rem)
            if (si3 >= rem && si3 - c3 < rem) { s_sel[0] = tid * 4 + 3; s_sel[1] = rem - (si3 - c3); }
            if (si2 >= rem && si2 - c2 < rem) { s_sel[0] = tid * 4 + 2; s_sel[1] = rem - (si2 - c2); }
            if (si1 >= rem && si1 - c1 < rem) { s_sel[0] = tid * 4 + 1; s_sel[1] = rem - (si1 - c1); }
            if (si0 >= rem && si0 - c0 < rem) { s_sel[0] = tid * 4 + 0; s_sel[1] = rem - (si0 - c0); }
        }
        __syncthreads();
        prefix |= s_sel[0] << shift;
        rem = s_sel[1];
        // no extra barrier needed: next write to s_sel is 2 barriers away
    }

    const unsigned tkey = prefix;  // exact k-th largest key; rem = # equals to keep

    // ---- Index-ordered rank among elements equal to tkey (block exclusive scan)
    unsigned cnt_eq = 0;
    #pragma unroll
    for (int j = 0; j < EPT; ++j) cnt_eq += (k[j] == tkey) ? 1u : 0u;

    const unsigned lane = tid & 63u, wid = (unsigned)tid >> 6;
    unsigned incl = cnt_eq;
    #pragma unroll
    for (int off = 1; off < 64; off <<= 1) {
        unsigned t = __shfl_up(incl, off, 64);
        if (lane >= (unsigned)off) incl += t;
    }
    if (lane == 63) s_wsum[wid] = incl;
    __syncthreads();
    unsigned ebase = incl - cnt_eq;  // exclusive within wave
    #pragma unroll
    for (unsigned w = 0; w < TPB / 64; ++w)
        if (w < wid) ebase += s_wsum[w];

    // ---- Emit: keep keys > tkey, plus the first `rem` (index order) keys == tkey
    float4 o[4];
    float* of = (float*)o;
    unsigned eqr = ebase;
    #pragma unroll
    for (int j = 0; j < EPT; ++j) {
        bool keep;
        if (k[j] > tkey)       keep = true;
        else if (k[j] == tkey) { keep = (eqr < rem); ++eqr; }
        else                   keep = false;
        of[j] = keep ? val_of(k[j]) : 0.0f;
    }
    float4* po = (float4*)(out + base);
    po[0] = o[0]; po[1] = o[1]; po[2] = o[2]; po[3] = o[3];
}

extern "C" void kernel_launch(void* const* d_in, const int* in_sizes, int n_in,
                              void* d_out, int out_size, void* d_ws, size_t ws_size,
                              hipStream_t stream) {
    const float* x = (const float*)d_in[0];
    float* out = (float*)d_out;
    const int rows = in_sizes[0] / D;  // 4*4096 = 16384
    topk_keep_kernel<<<dim3(rows), dim3(TPB), 0, stream>>>(x, out);
}

// Round 2
// 436.100 us; speedup vs baseline: 1.0400x; 1.0400x over previous
//
#include <hip/hip_runtime.h>

#define D     4096   // row length
#define KKEEP 512    // entries to keep per row
#define TPB   256    // threads per block (one block per row)
#define EPT   16     // elements per thread (D / TPB)
#define NB    2048   // histogram bins (11-bit digits; round 2 uses low 1024 only)
#define BPT   (NB / TPB)             // 8 bins per thread in the scan
#define HA(d) ((d) + ((d) >> 3))     // padded hist address: chunk base = 9*tid
#define HWORDS (NB + NB / 8)         // 2304 words

// Monotonic float -> uint key: preserves total order of floats as unsigned ints.
__device__ __forceinline__ unsigned key_of(float f) {
    unsigned u = __float_as_uint(f);
    return (u & 0x80000000u) ? ~u : (u | 0x80000000u);
}
// Exact inverse of key_of.
__device__ __forceinline__ float val_of(unsigned k) {
    unsigned u = (k & 0x80000000u) ? (k ^ 0x80000000u) : ~k;
    return __uint_as_float(u);
}

__global__ __launch_bounds__(TPB, 8)
void topk_keep_kernel(const float* __restrict__ x, float* __restrict__ out) {
    const int tid = threadIdx.x;
    const long base = (long)blockIdx.x * D + (long)tid * EPT;
    const unsigned lane = tid & 63u, wid = (unsigned)tid >> 6;

    // ---- Load 16 floats (4x float4, contiguous chunk per thread), keys in regs
    unsigned k[EPT];
    {
        const float4* px = (const float4*)(x + base);
        float4 f0 = px[0], f1 = px[1], f2 = px[2], f3 = px[3];
        k[ 0]=key_of(f0.x); k[ 1]=key_of(f0.y); k[ 2]=key_of(f0.z); k[ 3]=key_of(f0.w);
        k[ 4]=key_of(f1.x); k[ 5]=key_of(f1.y); k[ 6]=key_of(f1.z); k[ 7]=key_of(f1.w);
        k[ 8]=key_of(f2.x); k[ 9]=key_of(f2.y); k[10]=key_of(f2.z); k[11]=key_of(f2.w);
        k[12]=key_of(f3.x); k[13]=key_of(f3.y); k[14]=key_of(f3.z); k[15]=key_of(f3.w);
    }

    __shared__ unsigned hist[HWORDS];
    __shared__ unsigned s_wtot[4];   // per-wave chunk-total suffix sums
    __shared__ unsigned s_sel[2];    // [selected digit, new remaining]
    __shared__ unsigned s_wsum[4];   // per-wave equal-count totals (tie phase)

    unsigned prefix = 0;   // decided high bits of threshold key (in place)
    unsigned rem = KKEEP;  // rank still to satisfy within current prefix subset

    // ---- 3-round radix select, fields [31:21], [20:10], [9:0] (MSB first)
    #pragma unroll
    for (int r = 0; r < 3; ++r) {
        const int shift = (r == 0) ? 21 : (r == 1) ? 10 : 0;
        const unsigned mask = (r == 2) ? 1023u : 2047u;

        // zero (upper half stays zero in round 2 — harmless for the scan)
        #pragma unroll
        for (int i = 0; i < 9; ++i) hist[tid + i * TPB] = 0;
        __syncthreads();

        if (r == 0) {
            #pragma unroll
            for (int j = 0; j < EPT; ++j)
                atomicAdd(&hist[HA(k[j] >> 21)], 1u);
        } else {
            const int hs = (r == 1) ? 21 : 10;  // bits already decided
            #pragma unroll
            for (int j = 0; j < EPT; ++j)
                if ((k[j] >> hs) == (prefix >> hs))
                    atomicAdd(&hist[HA((k[j] >> shift) & mask)], 1u);
        }
        __syncthreads();

        // All-thread suffix scan: thread t owns bins [8t, 8t+8) at words 9t..9t+7
        unsigned c[BPT];
        unsigned ct = 0;
        {
            const int hb = tid * 9;
            #pragma unroll
            for (int i = 0; i < BPT; ++i) { c[i] = hist[hb + i]; ct += c[i]; }
        }
        // wave-level inclusive suffix scan of chunk totals
        unsigned s = ct;
        #pragma unroll
        for (int off = 1; off < 64; off <<= 1) {
            unsigned t = __shfl_down(s, off, 64);
            if (lane + (unsigned)off < 64u) s += t;
        }
        if (lane == 0) s_wtot[wid] = s;  // total of this wave's 512 bins
        __syncthreads();
        unsigned above = s - ct;         // higher-tid lanes within my wave
        #pragma unroll
        for (unsigned w = 0; w < 4; ++w)
            if (w > wid) above += s_wtot[w];
        // walk my 8 bins top-down; exactly one bin globally crosses `rem`
        unsigned run = above;
        #pragma unroll
        for (int i = BPT - 1; i >= 0; --i) {
            unsigned incl = run + c[i];
            if (incl >= rem && run < rem) {
                s_sel[0] = (unsigned)(tid * BPT + i);
                s_sel[1] = rem - run;
            }
            run = incl;
        }
        __syncthreads();
        prefix |= s_sel[0] << shift;
        rem = s_sel[1];
        // safe: next write to s_sel/s_wtot is ≥2 barriers away
    }

    const unsigned tkey = prefix;  // exact k-th largest key; rem = # equals to keep

    // ---- Index-ordered rank among elements equal to tkey (block exclusive scan)
    unsigned cnt_eq = 0;
    #pragma unroll
    for (int j = 0; j < EPT; ++j) cnt_eq += (k[j] == tkey) ? 1u : 0u;

    unsigned incl = cnt_eq;
    #pragma unroll
    for (int off = 1; off < 64; off <<= 1) {
        unsigned t = __shfl_up(incl, off, 64);
        if (lane >= (unsigned)off) incl += t;
    }
    if (lane == 63) s_wsum[wid] = incl;
    __syncthreads();
    unsigned ebase = incl - cnt_eq;  // exclusive within wave
    #pragma unroll
    for (unsigned w = 0; w < 4; ++w)
        if (w < wid) ebase += s_wsum[w];

    // ---- Emit: keep keys > tkey, plus the first `rem` (index order) keys == tkey
    float4 o[4];
    float* of = (float*)o;
    unsigned eqr = ebase;
    #pragma unroll
    for (int j = 0; j < EPT; ++j) {
        bool keep;
        if (k[j] > tkey)       keep = true;
        else if (k[j] == tkey) { keep = (eqr < rem); ++eqr; }
        else                   keep = false;
        of[j] = keep ? val_of(k[j]) : 0.0f;
    }
    float4* po = (float4*)(out + base);
    po[0] = o[0]; po[1] = o[1]; po[2] = o[2]; po[3] = o[3];
}

extern "C" void kernel_launch(void* const* d_in, const int* in_sizes, int n_in,
                              void* d_out, int out_size, void* d_ws, size_t ws_size,
                              hipStream_t stream) {
    const float* x = (const float*)d_in[0];
    float* out = (float*)d_out;
    const int rows = in_sizes[0] / D;  // 4*4096 = 16384
    topk_keep_kernel<<<dim3(rows), dim3(TPB), 0, stream>>>(x, out);
}

// Round 3
// 432.649 us; speedup vs baseline: 1.0483x; 1.0080x over previous
//
#include <hip/hip_runtime.h>

#define D     4096   // row length
#define KKEEP 512    // entries to keep per row
#define TPB   256    // threads per block (one block per row)
#define NSEG  4      // float4 segments per thread (D/4/TPB)
#define NB    2048   // histogram bins (11-bit digits; round 2 uses low 1024 only)
#define BPT   (NB / TPB)             // 8 bins per thread in the scan
#define HA(d) ((d) + ((d) >> 3))     // padded hist address: chunk base = 9*tid
#define HWORDS (NB + NB / 8)         // 2304 words

// Monotonic float -> uint key: preserves total order of floats as unsigned ints.
__device__ __forceinline__ unsigned key_of(float f) {
    unsigned u = __float_as_uint(f);
    return (u & 0x80000000u) ? ~u : (u | 0x80000000u);
}
// Exact inverse of key_of.
__device__ __forceinline__ float val_of(unsigned k) {
    unsigned u = (k & 0x80000000u) ? (k ^ 0x80000000u) : ~k;
    return __uint_as_float(u);
}

__global__ __launch_bounds__(TPB, 8)
void topk_keep_kernel(const float* __restrict__ x, float* __restrict__ out) {
    const int tid = threadIdx.x;
    const unsigned lane = tid & 63u, wid = (unsigned)tid >> 6;
    const float4* px = (const float4*)(x + (long)blockIdx.x * D);
    float4*       po = (float4*)(out + (long)blockIdx.x * D);

    // ---- Coalesced load: thread t owns float4 indices {t + 256*j}.
    // Element index of (j, t, c) = j*1024 + 4t + c  → (j,t,c) lex == index order.
    unsigned k[NSEG * 4];
    {
        float4 f0 = px[tid], f1 = px[tid + TPB], f2 = px[tid + 2 * TPB], f3 = px[tid + 3 * TPB];
        k[ 0]=key_of(f0.x); k[ 1]=key_of(f0.y); k[ 2]=key_of(f0.z); k[ 3]=key_of(f0.w);
        k[ 4]=key_of(f1.x); k[ 5]=key_of(f1.y); k[ 6]=key_of(f1.z); k[ 7]=key_of(f1.w);
        k[ 8]=key_of(f2.x); k[ 9]=key_of(f2.y); k[10]=key_of(f2.z); k[11]=key_of(f2.w);
        k[12]=key_of(f3.x); k[13]=key_of(f3.y); k[14]=key_of(f3.z); k[15]=key_of(f3.w);
    }

    __shared__ unsigned hist[HWORDS];
    __shared__ unsigned s_wtot[4];    // per-wave chunk totals (select scan)
    __shared__ unsigned s_sel[2];     // [selected digit, new remaining]
    __shared__ unsigned s_w01[4];     // tie phase: packed seg0|seg1 wave totals
    __shared__ unsigned s_w23[4];     // tie phase: packed seg2|seg3 wave totals

    unsigned prefix = 0;   // decided high bits of threshold key (in place)
    unsigned rem = KKEEP;  // rank still to satisfy within current prefix subset

    // ---- 3-round radix select, fields [31:21], [20:10], [9:0] (MSB first)
    #pragma unroll
    for (int r = 0; r < 3; ++r) {
        const int shift = (r == 0) ? 21 : (r == 1) ? 10 : 0;
        const unsigned mask = (r == 2) ? 1023u : 2047u;

        #pragma unroll
        for (int i = 0; i < 9; ++i) hist[tid + i * TPB] = 0;
        __syncthreads();

        if (r == 0) {
            #pragma unroll
            for (int j = 0; j < 16; ++j)
                atomicAdd(&hist[HA(k[j] >> 21)], 1u);
        } else {
            const int hs = (r == 1) ? 21 : 10;  // bits already decided
            #pragma unroll
            for (int j = 0; j < 16; ++j)
                if ((k[j] >> hs) == (prefix >> hs))
                    atomicAdd(&hist[HA((k[j] >> shift) & mask)], 1u);
        }
        __syncthreads();

        // All-thread suffix scan: thread t owns bins [8t, 8t+8) at words 9t..9t+7
        unsigned c[BPT];
        unsigned ct = 0;
        {
            const int hb = tid * 9;
            #pragma unroll
            for (int i = 0; i < BPT; ++i) { c[i] = hist[hb + i]; ct += c[i]; }
        }
        unsigned s = ct;  // wave inclusive suffix scan of chunk totals
        #pragma unroll
        for (int off = 1; off < 64; off <<= 1) {
            unsigned t = __shfl_down(s, off, 64);
            if (lane + (unsigned)off < 64u) s += t;
        }
        if (lane == 0) s_wtot[wid] = s;
        __syncthreads();
        unsigned above = s - ct;
        #pragma unroll
        for (unsigned w = 0; w < 4; ++w)
            if (w > wid) above += s_wtot[w];
        unsigned run = above;  // walk my 8 bins top-down; one bin crosses `rem`
        #pragma unroll
        for (int i = BPT - 1; i >= 0; --i) {
            unsigned incl = run + c[i];
            if (incl >= rem && run < rem) {
                s_sel[0] = (unsigned)(tid * BPT + i);
                s_sel[1] = rem - run;
            }
            run = incl;
        }
        __syncthreads();
        prefix |= s_sel[0] << shift;
        rem = s_sel[1];
    }

    const unsigned tkey = prefix;  // exact k-th largest key; rem = # equals to keep

    // ---- Tie-break rank in element-index order = (segment j, thread t, comp c).
    // Packed per-segment equal counts: p01 = e0 | e1<<16, p23 = e2 | e3<<16.
    unsigned e[NSEG];
    #pragma unroll
    for (int j = 0; j < NSEG; ++j) {
        unsigned c0 = (k[4*j+0] == tkey), c1 = (k[4*j+1] == tkey);
        unsigned c2 = (k[4*j+2] == tkey), c3 = (k[4*j+3] == tkey);
        e[j] = c0 + c1 + c2 + c3;
    }
    unsigned p01 = e[0] | (e[1] << 16);
    unsigned p23 = e[2] | (e[3] << 16);
    unsigned i01 = p01, i23 = p23;  // wave inclusive scans (sums ≤1024 per half)
    #pragma unroll
    for (int off = 1; off < 64; off <<= 1) {
        unsigned t0 = __shfl_up(i01, off, 64);
        unsigned t1 = __shfl_up(i23, off, 64);
        if (lane >= (unsigned)off) { i01 += t0; i23 += t1; }
    }
    if (lane == 63) { s_w01[wid] = i01; s_w23[wid] = i23; }
    __syncthreads();
    unsigned x01 = i01 - p01, x23 = i23 - p23;  // exclusive within wave
    #pragma unroll
    for (unsigned w = 0; w < 4; ++w)
        if (w < wid) { x01 += s_w01[w]; x23 += s_w23[w]; }
    const unsigned tot01 = s_w01[0] + s_w01[1] + s_w01[2] + s_w01[3];
    const unsigned tot23 = s_w23[0] + s_w23[1] + s_w23[2] + s_w23[3];
    const unsigned total0 = tot01 & 0xffffu, total1 = tot01 >> 16;
    const unsigned total2 = tot23 & 0xffffu;
    unsigned rank[NSEG];  // global equal-rank of my first equal in each segment
    rank[0] = (x01 & 0xffffu);
    rank[1] = total0 + (x01 >> 16);
    rank[2] = total0 + total1 + (x23 & 0xffffu);
    rank[3] = total0 + total1 + total2 + (x23 >> 16);

    // ---- Emit (coalesced): keep keys > tkey, plus equals with rank < rem
    #pragma unroll
    for (int j = 0; j < NSEG; ++j) {
        float4 o;
        unsigned eqr = rank[j];
        float* ofp = (float*)&o;
        #pragma unroll
        for (int c = 0; c < 4; ++c) {
            unsigned kk = k[4*j + c];
            bool keep;
            if (kk > tkey)       keep = true;
            else if (kk == tkey) { keep = (eqr < rem); ++eqr; }
            else                 keep = false;
            ofp[c] = keep ? val_of(kk) : 0.0f;
        }
        po[tid + j * TPB] = o;
    }
}

extern "C" void kernel_launch(void* const* d_in, const int* in_sizes, int n_in,
                              void* d_out, int out_size, void* d_ws, size_t ws_size,
                              hipStream_t stream) {
    const float* x = (const float*)d_in[0];
    float* out = (float*)d_out;
    const int rows = in_sizes[0] / D;  // 4*4096 = 16384
    topk_keep_kernel<<<dim3(rows), dim3(TPB), 0, stream>>>(x, out);
}